// Round 1
// baseline (1270.130 us; speedup 1.0000x reference)
//
#include <hip/hip_runtime.h>

#define H_ 1024
#define W_ 1024
#define BATCH_ 4
#define CIN_ 32
#define COUT_ 32
#define KSZ_ 9

#define TH 16
#define TW 16
#define HALO_H (TH + 6)          // 22
#define HALO_W (TW + 6)          // 22
#define NPIX (HALO_H * HALO_W)   // 484
#define NTAPS 29

typedef __attribute__((ext_vector_type(8))) short short8;
typedef __attribute__((ext_vector_type(4))) float f32x4;

struct Tap { int dy, dx; };

// taps with dy^2+dx^2 <= 9 (disk support of psi; boundary taps are exactly 0 but harmless)
#define TAPS_LIST \
  {-3,0}, \
  {-2,-2},{-2,-1},{-2,0},{-2,1},{-2,2}, \
  {-1,-2},{-1,-1},{-1,0},{-1,1},{-1,2}, \
  {0,-3},{0,-2},{0,-1},{0,0},{0,1},{0,2},{0,3}, \
  {1,-2},{1,-1},{1,0},{1,1},{1,2}, \
  {2,-2},{2,-1},{2,0},{2,1},{2,2}, \
  {3,0}

__device__ const Tap g_taps[NTAPS] = { TAPS_LIST };

__device__ __forceinline__ unsigned short f2bf(float f) {
    unsigned int u = __builtin_bit_cast(unsigned int, f);
    u = (u + 0x7FFFu + ((u >> 16) & 1u)) >> 16;   // RNE
    return (unsigned short)u;
}

// Build bf16 conv weights in A-fragment-friendly layout:
//   kw[t][q][oc][j]  (j = ic within quad, ic = q*8+j), flat bf16, 29*1024 elems.
__global__ void build_kw(const float* __restrict__ weight,
                         const float* __restrict__ psi,
                         unsigned short* __restrict__ kw) {
    int t = blockIdx.x;
    int a = g_taps[t].dy + 3;
    int bb = g_taps[t].dx + 3;
    float pv[KSZ_];
#pragma unroll
    for (int k = 0; k < KSZ_; ++k) pv[k] = psi[k * 49 + a * 7 + bb];
    for (int e = threadIdx.x; e < 1024; e += blockDim.x) {
        int q = e >> 8, rem = e & 255, oc = rem >> 3, j = rem & 7;
        int ic = q * 8 + j;
        float acc = 0.f;
#pragma unroll
        for (int k = 0; k < KSZ_; ++k) acc += pv[k] * weight[(oc * CIN_ + ic) * KSZ_ + k];
        kw[t * 1024 + e] = f2bf(acc);
    }
}

__global__ __launch_bounds__(256, 4)
void dconv(const float* __restrict__ x, const uint4* __restrict__ kw4,
           const float* __restrict__ bias, float* __restrict__ out) {
    // x tile in channel-quad planes: xt[q][pixel] = 8 bf16 (ic q*8..q*8+7) of that pixel
    __shared__ uint4 xt[4][NPIX];   // 30,976 B

    const int tid = threadIdx.x;
    const unsigned bid = blockIdx.x;
    const int txt = bid & 63;
    const int tyt = (bid >> 6) & 63;
    const int b   = bid >> 12;
    const int x0 = txt * TW, y0 = tyt * TH;
    const size_t plane = (size_t)H_ * W_;

    // ---------------- staging: global fp32 -> bf16 LDS ----------------
    for (int item = tid; item < 4 * NPIX; item += 256) {
        int q = item / NPIX;
        int p = item - q * NPIX;
        int ty = p / HALO_W;
        int tx = p - ty * HALO_W;
        int gy = y0 + ty - 3, gx = x0 + tx - 3;
        bool inb = (gy >= 0) & (gy < H_) & (gx >= 0) & (gx < W_);
        int cy = inb ? gy : 0, cx = inb ? gx : 0;
        const float* xp = x + (size_t)(b * CIN_ + q * 8) * plane + (size_t)cy * W_ + cx;
        float v[8];
#pragma unroll
        for (int j = 0; j < 8; ++j) v[j] = inb ? xp[(size_t)j * plane] : 0.f;
        uint4 pk;
        pk.x = (unsigned)f2bf(v[0]) | ((unsigned)f2bf(v[1]) << 16);
        pk.y = (unsigned)f2bf(v[2]) | ((unsigned)f2bf(v[3]) << 16);
        pk.z = (unsigned)f2bf(v[4]) | ((unsigned)f2bf(v[5]) << 16);
        pk.w = (unsigned)f2bf(v[6]) | ((unsigned)f2bf(v[7]) << 16);
        xt[q][p] = pk;
    }
    __syncthreads();

    // ---------------- compute: 29-tap implicit GEMM ----------------
    const int wv = tid >> 6, lane = tid & 63;
    const int p16 = lane & 15, quad = lane >> 4;

    f32x4 acc[4][2];
#pragma unroll
    for (int g = 0; g < 4; ++g) {
        acc[g][0] = f32x4{0.f, 0.f, 0.f, 0.f};
        acc[g][1] = f32x4{0.f, 0.f, 0.f, 0.f};
    }

    const uint4* bp = &xt[quad][0];
    int gbase[4];
#pragma unroll
    for (int g = 0; g < 4; ++g)
        gbase[g] = (wv * 4 + g + 3) * HALO_W + (p16 + 3);

    constexpr Tap taps[NTAPS] = { TAPS_LIST };
#pragma unroll
    for (int t = 0; t < NTAPS; ++t) {
        // A fragments: weights[oc = lane&15 (+16)][ic = quad*8 + j]
        short8 a0 = __builtin_bit_cast(short8, kw4[t * 128 + quad * 32 + p16]);
        short8 a1 = __builtin_bit_cast(short8, kw4[t * 128 + quad * 32 + 16 + p16]);
        const int toff = taps[t].dy * HALO_W + taps[t].dx;
#pragma unroll
        for (int g = 0; g < 4; ++g) {
            // B fragment: x[ic = quad*8 + j][pixel = (row, x0 + lane&15) + tap offset]
            short8 bf = __builtin_bit_cast(short8, bp[gbase[g] + toff]);
            acc[g][0] = __builtin_amdgcn_mfma_f32_16x16x32_bf16(a0, bf, acc[g][0], 0, 0, 0);
            acc[g][1] = __builtin_amdgcn_mfma_f32_16x16x32_bf16(a1, bf, acc[g][1], 0, 0, 0);
        }
    }

    // ---------------- epilogue: D[row=oc: quad*4+reg][col=pixel: lane&15] ----------------
    float bv[2][4];
#pragma unroll
    for (int h = 0; h < 2; ++h)
#pragma unroll
        for (int i = 0; i < 4; ++i) bv[h][i] = bias[h * 16 + quad * 4 + i];

    float* ob = out + (size_t)b * COUT_ * plane;
#pragma unroll
    for (int g = 0; g < 4; ++g) {
        int gy = y0 + wv * 4 + g;
#pragma unroll
        for (int h = 0; h < 2; ++h) {
#pragma unroll
            for (int i = 0; i < 4; ++i) {
                int oc = h * 16 + quad * 4 + i;
                ob[(size_t)oc * plane + (size_t)gy * W_ + x0 + p16] = acc[g][h][i] + bv[h][i];
            }
        }
    }
}

extern "C" void kernel_launch(void* const* d_in, const int* in_sizes, int n_in,
                              void* d_out, int out_size, void* d_ws, size_t ws_size,
                              hipStream_t stream) {
    const float* x      = (const float*)d_in[0];
    const float* weight = (const float*)d_in[1];
    const float* bias   = (const float*)d_in[2];
    const float* psi    = (const float*)d_in[3];
    float* out = (float*)d_out;
    unsigned short* kw = (unsigned short*)d_ws;   // 29*1024 bf16 = 59,392 B

    hipLaunchKernelGGL(build_kw, dim3(NTAPS), dim3(256), 0, stream, weight, psi, kw);
    hipLaunchKernelGGL(dconv, dim3(BATCH_ * (H_ / TH) * (W_ / TW)), dim3(256), 0, stream,
                       x, (const uint4*)kw, bias, out);
    (void)in_sizes; (void)n_in; (void)out_size; (void)ws_size;
}